// Round 18
// baseline (111.427 us; speedup 1.0000x reference)
//
#include <hip/hip_runtime.h>

// RGCN layer, basis decomposition — CSR-reordered formulation.
//
//   G[n][b][i] = sum_{e: dst[e]==n} (norm_e * w_comp[etype_e][b]) * h[src_e][i]
//   out[n][o]  = relu( sum_b sum_i G[n][b][i] * weight[b][i][o] + bias[o] )
//
// CSR build: LDS-privatized counting sort, zero global atomics (NCHUNK=64).
// Records 8B {src|etype<<16, norm-f32} (N <= 65536).
// Round-18: fused phase-1 aggregates TWO nodes in lockstep (interleaved
//   batch rounds) — 16 h-gathers in flight per wave instead of 8. Rounds
//   17's fused was still latency-bound (VALUBusy ~21%): the per-node batch
//   loop is fenced by sched_barriers, so MLP was capped at 8. Records/coeffs
//   stay scalarized (wave-uniform s_load); tails are clamped+masked 8-batches.

constexpr int NCHUNK = 64;   // edge chunks
constexpr int NRANGE = 4;    // node ranges (LDS bins = ceil(N/NRANGE))
constexpr int MAXBIN = 12800; // 51.2KB LDS; requires N <= NRANGE*MAXBIN

typedef unsigned int u32x4 __attribute__((ext_vector_type(4)));
typedef float f32x4 __attribute__((ext_vector_type(4)));

static __device__ __forceinline__ unsigned short f2bf(float f) {
    unsigned u = __float_as_uint(f);
    u = (u + 0x7fffu + ((u >> 16) & 1u)) >> 16;   // round-to-nearest-even
    return (unsigned short)u;
}
static __device__ __forceinline__ float bf2f(unsigned short v) {
    return __uint_as_float(((unsigned)v) << 16);
}

// ============================ prep: W->bf16 o-major  +  h->bf16 ============================
__global__ __launch_bounds__(256) void prep_kernel(const float* __restrict__ weight,
                                                   unsigned short* __restrict__ Wt,
                                                   const float* __restrict__ h,
                                                   unsigned short* __restrict__ hb,
                                                   int total4) {   // total4 = N*64/4
    int i = blockIdx.x * blockDim.x + threadIdx.x;
    int st = gridDim.x * blockDim.x;
    if (i < 16384) {
        int o = i >> 8, k = i & 255;
        Wt[i] = f2bf(weight[k * 64 + o]);
    }
    for (int q = i; q < total4; q += st) {
        float4 v = ((const float4*)h)[q];
        ushort4 o4;
        o4.x = f2bf(v.x); o4.y = f2bf(v.y); o4.z = f2bf(v.z); o4.w = f2bf(v.w);
        ((ushort4*)hb)[q] = o4;
    }
}

// ============================ hist (no global atomics) ============================

__global__ __launch_bounds__(256) void hist2_kernel(const int* __restrict__ dst,
                                                    int* __restrict__ counts,
                                                    int N, int E, int CH, int RS) {
    __shared__ int bins[MAXBIN];
    const int c = blockIdx.x / NRANGE;
    const int r = blockIdx.x % NRANGE;
    const int lo = r * RS;
    const int hi = (lo + RS < N) ? (lo + RS) : N;
    const int nbin = hi - lo;
    for (int i = threadIdx.x; i < nbin; i += 256) bins[i] = 0;
    __syncthreads();

    const int e0 = c * CH;
    const int e1 = (e0 + CH < E) ? (e0 + CH) : E;
    if (e0 < E) {
        const int cnt = e1 - e0;
        const int nq = cnt >> 2;
        const int4* d4p = (const int4*)(dst + e0);
        for (int q = threadIdx.x; q < nq; q += 256) {
            int4 d4 = d4p[q];
            if (d4.x >= lo && d4.x < hi) atomicAdd(&bins[d4.x - lo], 1);
            if (d4.y >= lo && d4.y < hi) atomicAdd(&bins[d4.y - lo], 1);
            if (d4.z >= lo && d4.z < hi) atomicAdd(&bins[d4.z - lo], 1);
            if (d4.w >= lo && d4.w < hi) atomicAdd(&bins[d4.w - lo], 1);
        }
        int rem = cnt & 3;
        if ((int)threadIdx.x < rem) {
            int d = dst[e0 + (nq << 2) + threadIdx.x];
            if (d >= lo && d < hi) atomicAdd(&bins[d - lo], 1);
        }
    }
    __syncthreads();
    int* crow = counts + (size_t)c * N + lo;
    for (int i = threadIdx.x; i < nbin; i += 256) crow[i] = bins[i];
}

// ============================ scan ============================

__global__ __launch_bounds__(256) void scan1_kernel(const int* __restrict__ counts,
                                                    int* __restrict__ bsum, int N) {
    __shared__ int s[256];
    int t = threadIdx.x;
    int n = blockIdx.x * 256 + t;
    int sum = 0;
    if (n < N) {
        for (int c = 0; c < NCHUNK; ++c) sum += counts[(size_t)c * N + n];
    }
    s[t] = sum;
    __syncthreads();
    for (int off = 128; off > 0; off >>= 1) {
        if (t < off) s[t] += s[t + off];
        __syncthreads();
    }
    if (t == 0) bsum[blockIdx.x] = s[0];
}

// merged scan2+scan3
__global__ __launch_bounds__(256) void scan23_kernel(int* __restrict__ counts,
                                                     const int* __restrict__ bsum, int nb,
                                                     int* __restrict__ offsets,
                                                     int N, int E) {
    __shared__ int sb[256];
    __shared__ int s[256];
    int t = threadIdx.x;
    sb[t] = (t < nb) ? bsum[t] : 0;
    __syncthreads();
    for (int off = 1; off < 256; off <<= 1) {
        int x = (t >= off) ? sb[t - off] : 0;
        __syncthreads();
        sb[t] += x;
        __syncthreads();
    }
    int n = blockIdx.x * 256 + t;
    int sum = 0;
    if (n < N) {
        for (int c = 0; c < NCHUNK; ++c) sum += counts[(size_t)c * N + n];
    }
    s[t] = sum;
    __syncthreads();
    for (int off = 1; off < 256; off <<= 1) {
        int x = (t >= off) ? s[t - off] : 0;
        __syncthreads();
        s[t] += x;
        __syncthreads();
    }
    const int blockpre = (blockIdx.x > 0) ? sb[blockIdx.x - 1] : 0;
    if (n < N) {
        int run = s[t] - sum + blockpre;
        offsets[n] = run;
        for (int c = 0; c < NCHUNK; ++c) {
            int v = counts[(size_t)c * N + n];
            counts[(size_t)c * N + n] = run;
            run += v;
        }
    }
    if (blockIdx.x == 0 && t == 0) offsets[N] = E;
}

// ============================ fill (LDS cursors, 8B records) ============================

__global__ __launch_bounds__(256) void fill2_kernel(const int* __restrict__ src,
                                                    const int* __restrict__ dst,
                                                    const int* __restrict__ etype,
                                                    const float* __restrict__ norm,
                                                    const int* __restrict__ offs,
                                                    uint2* __restrict__ packed,
                                                    int N, int E, int CH, int RS) {
    __shared__ int cur[MAXBIN];
    const int c = blockIdx.x / NRANGE;
    const int r = blockIdx.x % NRANGE;
    const int lo = r * RS;
    const int hi = (lo + RS < N) ? (lo + RS) : N;
    const int nbin = hi - lo;
    const int* orow = offs + (size_t)c * N + lo;
    for (int i = threadIdx.x; i < nbin; i += 256) cur[i] = orow[i];
    __syncthreads();

    const int e0 = c * CH;
    const int e1 = (e0 + CH < E) ? (e0 + CH) : E;
    if (e0 >= E) return;
    const int cnt = e1 - e0;
    const int nq = cnt >> 2;
    const int4* d4p = (const int4*)(dst + e0);
    const int4* s4p = (const int4*)(src + e0);
    const int4* t4p = (const int4*)(etype + e0);
    const float4* n4p = (const float4*)(norm + e0);
    for (int q = threadIdx.x; q < nq; q += 256) {
        int4 d4 = d4p[q];
        int4 s4 = s4p[q];
        int4 t4 = t4p[q];
        float4 n4 = n4p[q];
        if (d4.x >= lo && d4.x < hi) {
            int pos = atomicAdd(&cur[d4.x - lo], 1);
            packed[pos] = make_uint2((unsigned)s4.x | ((unsigned)t4.x << 16),
                                     __float_as_uint(n4.x));
        }
        if (d4.y >= lo && d4.y < hi) {
            int pos = atomicAdd(&cur[d4.y - lo], 1);
            packed[pos] = make_uint2((unsigned)s4.y | ((unsigned)t4.y << 16),
                                     __float_as_uint(n4.y));
        }
        if (d4.z >= lo && d4.z < hi) {
            int pos = atomicAdd(&cur[d4.z - lo], 1);
            packed[pos] = make_uint2((unsigned)s4.z | ((unsigned)t4.z << 16),
                                     __float_as_uint(n4.z));
        }
        if (d4.w >= lo && d4.w < hi) {
            int pos = atomicAdd(&cur[d4.w - lo], 1);
            packed[pos] = make_uint2((unsigned)s4.w | ((unsigned)t4.w << 16),
                                     __float_as_uint(n4.w));
        }
    }
    int rem = cnt & 3;
    if ((int)threadIdx.x < rem) {
        int i = e0 + (nq << 2) + threadIdx.x;
        int d = dst[i];
        if (d >= lo && d < hi) {
            int pos = atomicAdd(&cur[d - lo], 1);
            packed[pos] = make_uint2((unsigned)src[i] | ((unsigned)etype[i] << 16),
                                     __float_as_uint(norm[i]));
        }
    }
}

// ============================ Fused aggregate + MFMA transform ============================
// Block = 4 waves = 2 tiles; wave (p, half) aggregates 8 nodes as 4 PAIRS in
// lockstep (16 gathers in flight), stages bf16 rows in the shared LDS tile,
// __syncthreads, then computes o-tiles {2*half, 2*half+1} via MFMA.
__global__ __launch_bounds__(256) void fused_kernel(const uint2* __restrict__ packed,
                                                    const int* __restrict__ offsets,
                                                    const unsigned short* __restrict__ hb,
                                                    const float4* __restrict__ wc4,
                                                    const unsigned short* __restrict__ Wt,
                                                    const float* __restrict__ bias,
                                                    float* __restrict__ out, int N) {
    __shared__ unsigned short gt[2][16][272];
    const int t = threadIdx.x;
    const int lane = t & 63;
    const int wv = __builtin_amdgcn_readfirstlane(t >> 6);   // provably uniform
    const int p = wv >> 1;
    const int half = wv & 1;
    const int l15 = lane & 15;
    const int lg = lane >> 4;
    const int tile = __builtin_amdgcn_readfirstlane(blockIdx.x * 2 + p);
    const int ntiles = (N + 15) >> 4;
    const bool active = (tile < ntiles);
    const int n0 = tile << 4;

    // ---------------- Phase 1: aggregate 8 nodes as 4 interleaved pairs ----------------
    if (active) {
        for (int jp = 0; jp < 4; ++jp) {
            const int jjA = half * 8 + jp * 2;
            const int jjB = jjA + 1;
            const int nA = n0 + jjA;
            const int nB = n0 + jjB;
            float gA0 = 0.f, gA1 = 0.f, gA2 = 0.f, gA3 = 0.f;
            float gB0 = 0.f, gB1 = 0.f, gB2 = 0.f, gB3 = 0.f;
            int eA = 0, eAend = 0, eB = 0, eBend = 0;
            if (nA < N) { eA = offsets[nA]; eAend = offsets[nA + 1]; }
            if (nB < N) { eB = offsets[nB]; eBend = offsets[nB + 1]; }

            while (eA < eAend || eB < eBend) {
                const bool doA = (eA < eAend);
                const bool doB = (eB < eBend);
                uint2 rA[8], rB[8];
                if (doA) {
#pragma unroll
                    for (int k = 0; k < 8; ++k) {
                        int idx = eA + k;
                        idx = (idx < eAend) ? idx : (eAend - 1);
                        rA[k] = packed[idx];
                    }
                }
                if (doB) {
#pragma unroll
                    for (int k = 0; k < 8; ++k) {
                        int idx = eB + k;
                        idx = (idx < eBend) ? idx : (eBend - 1);
                        rB[k] = packed[idx];
                    }
                }
                __builtin_amdgcn_sched_barrier(0);
                float hvA[8], hvB[8];
                float4 cA[8], cB[8];
                if (doA) {
#pragma unroll
                    for (int k = 0; k < 8; ++k) {
                        unsigned w0 = rA[k].x;
                        hvA[k] = bf2f(hb[(size_t)(w0 & 0xffffu) * 64 + lane]);
                        cA[k] = wc4[w0 >> 16];
                    }
                }
                if (doB) {
#pragma unroll
                    for (int k = 0; k < 8; ++k) {
                        unsigned w0 = rB[k].x;
                        hvB[k] = bf2f(hb[(size_t)(w0 & 0xffffu) * 64 + lane]);
                        cB[k] = wc4[w0 >> 16];
                    }
                }
                __builtin_amdgcn_sched_barrier(0);
                if (doA) {
                    const int remA = eAend - eA;
#pragma unroll
                    for (int k = 0; k < 8; ++k) {
                        float nmv = (k < remA) ? __uint_as_float(rA[k].y) : 0.f;
                        float a = nmv * hvA[k];
                        gA0 = fmaf(cA[k].x, a, gA0);
                        gA1 = fmaf(cA[k].y, a, gA1);
                        gA2 = fmaf(cA[k].z, a, gA2);
                        gA3 = fmaf(cA[k].w, a, gA3);
                    }
                    eA += 8;
                }
                if (doB) {
                    const int remB = eBend - eB;
#pragma unroll
                    for (int k = 0; k < 8; ++k) {
                        float nmv = (k < remB) ? __uint_as_float(rB[k].y) : 0.f;
                        float a = nmv * hvB[k];
                        gB0 = fmaf(cB[k].x, a, gB0);
                        gB1 = fmaf(cB[k].y, a, gB1);
                        gB2 = fmaf(cB[k].z, a, gB2);
                        gB3 = fmaf(cB[k].w, a, gB3);
                    }
                    eB += 8;
                }
            }
            gt[p][jjA][lane]       = f2bf(gA0);
            gt[p][jjA][64 + lane]  = f2bf(gA1);
            gt[p][jjA][128 + lane] = f2bf(gA2);
            gt[p][jjA][192 + lane] = f2bf(gA3);
            gt[p][jjB][lane]       = f2bf(gB0);
            gt[p][jjB][64 + lane]  = f2bf(gB1);
            gt[p][jjB][128 + lane] = f2bf(gB2);
            gt[p][jjB][192 + lane] = f2bf(gB3);
        }
    }
    __syncthreads();    // tile rows come from both waves of the pair
    if (!active) return;

    // ---------------- Phase 2: MFMA for o-tiles {2*half, 2*half+1} ----------------
    const int ot0 = half * 2;
    float bo0 = bias[(ot0 + 0) * 16 + l15];
    float bo1 = bias[(ot0 + 1) * 16 + l15];

    f32x4 a0 = {0.f, 0.f, 0.f, 0.f}, a1 = {0.f, 0.f, 0.f, 0.f};
#pragma unroll
    for (int ks = 0; ks < 8; ++ks) {
        u32x4 af = *reinterpret_cast<const u32x4*>(&gt[p][l15][ks * 32 + lg * 8]);
        u32x4 b0 = *reinterpret_cast<const u32x4*>(Wt + ((ot0 + 0) * 16 + l15) * 256 + ks * 32 + lg * 8);
        u32x4 b1 = *reinterpret_cast<const u32x4*>(Wt + ((ot0 + 1) * 16 + l15) * 256 + ks * 32 + lg * 8);
        asm volatile("v_mfma_f32_16x16x32_bf16 %0, %1, %2, %0"
                     : "+v"(a0) : "v"(af), "v"(b0));
        asm volatile("v_mfma_f32_16x16x32_bf16 %0, %1, %2, %0"
                     : "+v"(a1) : "v"(af), "v"(b1));
    }
    asm volatile("s_nop 7\n\ts_nop 7" ::: "memory");

#pragma unroll
    for (int r = 0; r < 4; ++r) {
        const int n = n0 + lg * 4 + r;
        if (n < N) {
            float* orow = out + (size_t)n * 64 + l15 + ot0 * 16;
            float v0 = a0[r] + bo0;
            float v1 = a1[r] + bo1;
            orow[0]  = v0 > 0.f ? v0 : 0.f;
            orow[16] = v1 > 0.f ? v1 : 0.f;
        }
    }
}

// ============================ Fallback path ============================

__global__ __launch_bounds__(256) void hb_kernel(const float* __restrict__ h,
                                                 const float* __restrict__ weight,
                                                 float* __restrict__ Hb, int N) {
    __shared__ float sh[16][64];
    const int t = threadIdx.x;
    const int b = t >> 6;
    const int o = t & 63;
    float wcol[64];
#pragma unroll
    for (int i = 0; i < 64; ++i) wcol[i] = weight[b * 4096 + i * 64 + o];
    for (int node0 = blockIdx.x * 16; node0 < N; node0 += gridDim.x * 16) {
        __syncthreads();
#pragma unroll
        for (int p = 0; p < 4; ++p) {
            int idx = p * 256 + t;
            int r = idx >> 6, c = idx & 63;
            int node = node0 + r;
            sh[r][c] = (node < N) ? h[(size_t)node * 64 + c] : 0.f;
        }
        __syncthreads();
        int rmax = (N - node0 < 16) ? (N - node0) : 16;
        for (int r = 0; r < rmax; ++r) {
            float acc = 0.f;
#pragma unroll
            for (int i = 0; i < 64; ++i) acc += sh[r][i] * wcol[i];
            Hb[(size_t)(node0 + r) * 256 + t] = acc;
        }
    }
}

__global__ __launch_bounds__(256) void edge_kernel(const float* __restrict__ Hb,
                                                   const float* __restrict__ w_comp,
                                                   const float* __restrict__ edge_norm,
                                                   const int* __restrict__ src,
                                                   const int* __restrict__ dst,
                                                   const int* __restrict__ etype,
                                                   float* __restrict__ out, int E) {
    const int lane = threadIdx.x & 63;
    const int gwave = (blockIdx.x * blockDim.x + threadIdx.x) >> 6;
    const int nwaves = (gridDim.x * blockDim.x) >> 6;
    const int chunk = (E + nwaves - 1) / nwaves;
    const int e0 = gwave * chunk;
    const int e1 = (e0 + chunk < E) ? (e0 + chunk) : E;
    for (int e = e0; e < e1; ++e) {
        int s = src[e];
        int d = dst[e];
        int r = etype[e];
        float nm = edge_norm[e];
        const float* hbp = Hb + (size_t)s * 256;
        const float* cf = w_comp + r * 4;
        float v = cf[0] * hbp[lane] + cf[1] * hbp[64 + lane] + cf[2] * hbp[128 + lane] +
                  cf[3] * hbp[192 + lane];
        atomicAdd(&out[(size_t)d * 64 + lane], v * nm);
    }
}

__global__ __launch_bounds__(256) void bias_relu_kernel(float* __restrict__ out,
                                                        const float* __restrict__ bias,
                                                        int total) {
    int i = blockIdx.x * blockDim.x + threadIdx.x;
    int stride = gridDim.x * blockDim.x;
    for (; i < total; i += stride) {
        float v = out[i] + bias[i & 63];
        out[i] = v > 0.f ? v : 0.f;
    }
}

// ============================ Launch ============================

extern "C" void kernel_launch(void* const* d_in, const int* in_sizes, int n_in,
                              void* d_out, int out_size, void* d_ws, size_t ws_size,
                              hipStream_t stream) {
    const float* h         = (const float*)d_in[0];
    const float* weight    = (const float*)d_in[1];
    const float* w_comp    = (const float*)d_in[2];
    const float* bias      = (const float*)d_in[3];
    const float* edge_norm = (const float*)d_in[4];
    const int*   src       = (const int*)d_in[5];
    const int*   dst       = (const int*)d_in[6];
    const int*   etype     = (const int*)d_in[7];
    float* out = (float*)d_out;

    const int N = in_sizes[0] / 64;
    const int E = in_sizes[4];
    const int nb = (N + 255) / 256;
    const int CH = (((E + NCHUNK - 1) / NCHUNK) + 3) & ~3;   // chunk size, x4 aligned
    const int RS = (N + NRANGE - 1) / NRANGE;                // bins per range

    // workspace: counts | packed | offsets,bsum | Wt | hb
    size_t cntBytes    = (size_t)NCHUNK * N * sizeof(int);
    size_t packedBytes = (size_t)E * 8;
    size_t offBytes    = (size_t)(N + 1) * sizeof(int);
    size_t bsumBytes   = (size_t)nb * sizeof(int);
    size_t wtBytes     = (size_t)64 * 256 * sizeof(unsigned short);
    size_t hbBytes     = (size_t)N * 64 * sizeof(unsigned short);
    size_t need        = cntBytes + packedBytes + offBytes + bsumBytes + wtBytes + hbBytes + 16384;

    if (ws_size >= need && nb <= 256 && RS <= MAXBIN && N <= 65536) {
        char* p = (char*)d_ws;
        int* counts   = (int*)p;
        uint2* packed = (uint2*)(p + cntBytes);
        int* offsets  = (int*)(p + cntBytes + packedBytes);
        int* bsum     = offsets + (N + 1);
        size_t wtOff  = ((cntBytes + packedBytes + offBytes + bsumBytes) + 255) & ~(size_t)255;
        unsigned short* Wt = (unsigned short*)(p + wtOff);
        size_t hbOff  = (wtOff + wtBytes + 255) & ~(size_t)255;
        unsigned short* hb = (unsigned short*)(p + hbOff);

        prep_kernel<<<1024, 256, 0, stream>>>(weight, Wt, h, hb, N * 16);
        hist2_kernel<<<NCHUNK * NRANGE, 256, 0, stream>>>(dst, counts, N, E, CH, RS);
        scan1_kernel<<<nb, 256, 0, stream>>>(counts, bsum, N);
        scan23_kernel<<<nb, 256, 0, stream>>>(counts, bsum, nb, offsets, N, E);
        fill2_kernel<<<NCHUNK * NRANGE, 256, 0, stream>>>(src, dst, etype, edge_norm,
                                                          counts, packed, N, E, CH, RS);
        const int ntiles = (N + 15) >> 4;
        const int fblocks = (ntiles + 1) >> 1;
        fused_kernel<<<fblocks, 256, 0, stream>>>(packed, offsets, hb, (const float4*)w_comp,
                                                  Wt, bias, out, N);
    } else if (ws_size >= (size_t)N * 256 * sizeof(float)) {
        float* Hb = (float*)d_ws;
        hipMemsetAsync(d_out, 0, (size_t)N * 64 * sizeof(float), stream);
        hb_kernel<<<1024, 256, 0, stream>>>(h, weight, Hb, N);
        edge_kernel<<<2048, 256, 0, stream>>>(Hb, w_comp, edge_norm, src, dst, etype, out, E);
        bias_relu_kernel<<<2048, 256, 0, stream>>>(out, bias, N * 64);
    }
}

// Round 19
// 87.836 us; speedup vs baseline: 1.2686x; 1.2686x over previous
//
#include <hip/hip_runtime.h>

// RGCN layer, basis decomposition — CSR-reordered formulation.
//
//   G[n][b][i] = sum_{e: dst[e]==n} (norm_e * w_comp[etype_e][b]) * h[src_e][i]
//   out[n][o]  = relu( sum_b sum_i G[n][b][i] * weight[b][i][o] + bias[o] )
//
// CSR build: LDS-privatized counting sort, zero global atomics (NCHUNK=64).
// Records 8B {src|etype<<16, norm-f32} (N <= 65536).
// Round-19: revert round-18's pair-interleave (wave-uniform doA/doB branches
//   made regalloc serialize the loads: VGPR 24, fused 58us). Back to round-17's
//   per-node loop, but 4 waves/tile: each wave aggregates 4 nodes + computes
//   1 o-tile. Grid 2x (3125 blocks, 12/CU), LDS 8.7KB -> occupancy capped by
//   the 32-wave/CU limit, double round-17's resident waves.

constexpr int NCHUNK = 64;   // edge chunks
constexpr int NRANGE = 4;    // node ranges (LDS bins = ceil(N/NRANGE))
constexpr int MAXBIN = 12800; // 51.2KB LDS; requires N <= NRANGE*MAXBIN

typedef unsigned int u32x4 __attribute__((ext_vector_type(4)));
typedef float f32x4 __attribute__((ext_vector_type(4)));

static __device__ __forceinline__ unsigned short f2bf(float f) {
    unsigned u = __float_as_uint(f);
    u = (u + 0x7fffu + ((u >> 16) & 1u)) >> 16;   // round-to-nearest-even
    return (unsigned short)u;
}
static __device__ __forceinline__ float bf2f(unsigned short v) {
    return __uint_as_float(((unsigned)v) << 16);
}

// ============================ prep: W->bf16 o-major  +  h->bf16 ============================
__global__ __launch_bounds__(256) void prep_kernel(const float* __restrict__ weight,
                                                   unsigned short* __restrict__ Wt,
                                                   const float* __restrict__ h,
                                                   unsigned short* __restrict__ hb,
                                                   int total4) {   // total4 = N*64/4
    int i = blockIdx.x * blockDim.x + threadIdx.x;
    int st = gridDim.x * blockDim.x;
    if (i < 16384) {
        int o = i >> 8, k = i & 255;
        Wt[i] = f2bf(weight[k * 64 + o]);
    }
    for (int q = i; q < total4; q += st) {
        float4 v = ((const float4*)h)[q];
        ushort4 o4;
        o4.x = f2bf(v.x); o4.y = f2bf(v.y); o4.z = f2bf(v.z); o4.w = f2bf(v.w);
        ((ushort4*)hb)[q] = o4;
    }
}

// ============================ hist (no global atomics) ============================

__global__ __launch_bounds__(256) void hist2_kernel(const int* __restrict__ dst,
                                                    int* __restrict__ counts,
                                                    int N, int E, int CH, int RS) {
    __shared__ int bins[MAXBIN];
    const int c = blockIdx.x / NRANGE;
    const int r = blockIdx.x % NRANGE;
    const int lo = r * RS;
    const int hi = (lo + RS < N) ? (lo + RS) : N;
    const int nbin = hi - lo;
    for (int i = threadIdx.x; i < nbin; i += 256) bins[i] = 0;
    __syncthreads();

    const int e0 = c * CH;
    const int e1 = (e0 + CH < E) ? (e0 + CH) : E;
    if (e0 < E) {
        const int cnt = e1 - e0;
        const int nq = cnt >> 2;
        const int4* d4p = (const int4*)(dst + e0);
        for (int q = threadIdx.x; q < nq; q += 256) {
            int4 d4 = d4p[q];
            if (d4.x >= lo && d4.x < hi) atomicAdd(&bins[d4.x - lo], 1);
            if (d4.y >= lo && d4.y < hi) atomicAdd(&bins[d4.y - lo], 1);
            if (d4.z >= lo && d4.z < hi) atomicAdd(&bins[d4.z - lo], 1);
            if (d4.w >= lo && d4.w < hi) atomicAdd(&bins[d4.w - lo], 1);
        }
        int rem = cnt & 3;
        if ((int)threadIdx.x < rem) {
            int d = dst[e0 + (nq << 2) + threadIdx.x];
            if (d >= lo && d < hi) atomicAdd(&bins[d - lo], 1);
        }
    }
    __syncthreads();
    int* crow = counts + (size_t)c * N + lo;
    for (int i = threadIdx.x; i < nbin; i += 256) crow[i] = bins[i];
}

// ============================ scan ============================

__global__ __launch_bounds__(256) void scan1_kernel(const int* __restrict__ counts,
                                                    int* __restrict__ bsum, int N) {
    __shared__ int s[256];
    int t = threadIdx.x;
    int n = blockIdx.x * 256 + t;
    int sum = 0;
    if (n < N) {
        for (int c = 0; c < NCHUNK; ++c) sum += counts[(size_t)c * N + n];
    }
    s[t] = sum;
    __syncthreads();
    for (int off = 128; off > 0; off >>= 1) {
        if (t < off) s[t] += s[t + off];
        __syncthreads();
    }
    if (t == 0) bsum[blockIdx.x] = s[0];
}

// merged scan2+scan3
__global__ __launch_bounds__(256) void scan23_kernel(int* __restrict__ counts,
                                                     const int* __restrict__ bsum, int nb,
                                                     int* __restrict__ offsets,
                                                     int N, int E) {
    __shared__ int sb[256];
    __shared__ int s[256];
    int t = threadIdx.x;
    sb[t] = (t < nb) ? bsum[t] : 0;
    __syncthreads();
    for (int off = 1; off < 256; off <<= 1) {
        int x = (t >= off) ? sb[t - off] : 0;
        __syncthreads();
        sb[t] += x;
        __syncthreads();
    }
    int n = blockIdx.x * 256 + t;
    int sum = 0;
    if (n < N) {
        for (int c = 0; c < NCHUNK; ++c) sum += counts[(size_t)c * N + n];
    }
    s[t] = sum;
    __syncthreads();
    for (int off = 1; off < 256; off <<= 1) {
        int x = (t >= off) ? s[t - off] : 0;
        __syncthreads();
        s[t] += x;
        __syncthreads();
    }
    const int blockpre = (blockIdx.x > 0) ? sb[blockIdx.x - 1] : 0;
    if (n < N) {
        int run = s[t] - sum + blockpre;
        offsets[n] = run;
        for (int c = 0; c < NCHUNK; ++c) {
            int v = counts[(size_t)c * N + n];
            counts[(size_t)c * N + n] = run;
            run += v;
        }
    }
    if (blockIdx.x == 0 && t == 0) offsets[N] = E;
}

// ============================ fill (LDS cursors, 8B records) ============================

__global__ __launch_bounds__(256) void fill2_kernel(const int* __restrict__ src,
                                                    const int* __restrict__ dst,
                                                    const int* __restrict__ etype,
                                                    const float* __restrict__ norm,
                                                    const int* __restrict__ offs,
                                                    uint2* __restrict__ packed,
                                                    int N, int E, int CH, int RS) {
    __shared__ int cur[MAXBIN];
    const int c = blockIdx.x / NRANGE;
    const int r = blockIdx.x % NRANGE;
    const int lo = r * RS;
    const int hi = (lo + RS < N) ? (lo + RS) : N;
    const int nbin = hi - lo;
    const int* orow = offs + (size_t)c * N + lo;
    for (int i = threadIdx.x; i < nbin; i += 256) cur[i] = orow[i];
    __syncthreads();

    const int e0 = c * CH;
    const int e1 = (e0 + CH < E) ? (e0 + CH) : E;
    if (e0 >= E) return;
    const int cnt = e1 - e0;
    const int nq = cnt >> 2;
    const int4* d4p = (const int4*)(dst + e0);
    const int4* s4p = (const int4*)(src + e0);
    const int4* t4p = (const int4*)(etype + e0);
    const float4* n4p = (const float4*)(norm + e0);
    for (int q = threadIdx.x; q < nq; q += 256) {
        int4 d4 = d4p[q];
        int4 s4 = s4p[q];
        int4 t4 = t4p[q];
        float4 n4 = n4p[q];
        if (d4.x >= lo && d4.x < hi) {
            int pos = atomicAdd(&cur[d4.x - lo], 1);
            packed[pos] = make_uint2((unsigned)s4.x | ((unsigned)t4.x << 16),
                                     __float_as_uint(n4.x));
        }
        if (d4.y >= lo && d4.y < hi) {
            int pos = atomicAdd(&cur[d4.y - lo], 1);
            packed[pos] = make_uint2((unsigned)s4.y | ((unsigned)t4.y << 16),
                                     __float_as_uint(n4.y));
        }
        if (d4.z >= lo && d4.z < hi) {
            int pos = atomicAdd(&cur[d4.z - lo], 1);
            packed[pos] = make_uint2((unsigned)s4.z | ((unsigned)t4.z << 16),
                                     __float_as_uint(n4.z));
        }
        if (d4.w >= lo && d4.w < hi) {
            int pos = atomicAdd(&cur[d4.w - lo], 1);
            packed[pos] = make_uint2((unsigned)s4.w | ((unsigned)t4.w << 16),
                                     __float_as_uint(n4.w));
        }
    }
    int rem = cnt & 3;
    if ((int)threadIdx.x < rem) {
        int i = e0 + (nq << 2) + threadIdx.x;
        int d = dst[i];
        if (d >= lo && d < hi) {
            int pos = atomicAdd(&cur[d - lo], 1);
            packed[pos] = make_uint2((unsigned)src[i] | ((unsigned)etype[i] << 16),
                                     __float_as_uint(norm[i]));
        }
    }
}

// ============================ Fused aggregate + MFMA transform (4 waves/tile) ============================
// Block = 4 waves = ONE tile. Wave wv aggregates nodes n0+wv*4..+3 (round-17
// per-node loop: full 8-batches + bounded masked tail), stages bf16 rows in
// the shared LDS tile; __syncthreads; computes o-tile wv via 8 MFMA.
__global__ __launch_bounds__(256) void fused_kernel(const uint2* __restrict__ packed,
                                                    const int* __restrict__ offsets,
                                                    const unsigned short* __restrict__ hb,
                                                    const float4* __restrict__ wc4,
                                                    const unsigned short* __restrict__ Wt,
                                                    const float* __restrict__ bias,
                                                    float* __restrict__ out, int N) {
    __shared__ unsigned short gt[16][272];
    const int t = threadIdx.x;
    const int lane = t & 63;
    const int wv = __builtin_amdgcn_readfirstlane(t >> 6);   // provably uniform
    const int l15 = lane & 15;
    const int lg = lane >> 4;
    const int n0 = __builtin_amdgcn_readfirstlane(blockIdx.x << 4);

    // ---------------- Phase 1: aggregate 4 nodes ----------------
    for (int j = 0; j < 4; ++j) {
        const int jj = wv * 4 + j;
        const int n = n0 + jj;
        float g0 = 0.f, g1 = 0.f, g2 = 0.f, g3 = 0.f;
        if (n < N) {
            const int e0 = offsets[n];
            const int e1 = offsets[n + 1];
            int e = e0;
            for (; e + 8 <= e1; e += 8) {
                uint2 r[8];
#pragma unroll
                for (int k = 0; k < 8; ++k) r[k] = packed[e + k];
                __builtin_amdgcn_sched_barrier(0);
                float hv[8];
                float4 c[8];
#pragma unroll
                for (int k = 0; k < 8; ++k) {
                    unsigned w0 = r[k].x;
                    hv[k] = bf2f(hb[(size_t)(w0 & 0xffffu) * 64 + lane]);
                    c[k] = wc4[w0 >> 16];
                }
                __builtin_amdgcn_sched_barrier(0);
#pragma unroll
                for (int k = 0; k < 8; ++k) {
                    float a = __uint_as_float(r[k].y) * hv[k];
                    g0 = fmaf(c[k].x, a, g0);
                    g1 = fmaf(c[k].y, a, g1);
                    g2 = fmaf(c[k].z, a, g2);
                    g3 = fmaf(c[k].w, a, g3);
                }
            }
            const int rem = e1 - e;
            if (rem > 4) {          // masked 8-batch, waste <= 3
                uint2 r[8];
#pragma unroll
                for (int k = 0; k < 8; ++k) {
                    int idx = e + k;
                    idx = (idx < e1) ? idx : (e1 - 1);
                    r[k] = packed[idx];
                }
                __builtin_amdgcn_sched_barrier(0);
                float hv[8];
                float4 c[8];
#pragma unroll
                for (int k = 0; k < 8; ++k) {
                    unsigned w0 = r[k].x;
                    hv[k] = bf2f(hb[(size_t)(w0 & 0xffffu) * 64 + lane]);
                    c[k] = wc4[w0 >> 16];
                }
                __builtin_amdgcn_sched_barrier(0);
#pragma unroll
                for (int k = 0; k < 8; ++k) {
                    float nmv = (k < rem) ? __uint_as_float(r[k].y) : 0.f;
                    float a = nmv * hv[k];
                    g0 = fmaf(c[k].x, a, g0);
                    g1 = fmaf(c[k].y, a, g1);
                    g2 = fmaf(c[k].z, a, g2);
                    g3 = fmaf(c[k].w, a, g3);
                }
            } else if (rem > 0) {   // masked 4-batch, waste <= 3
                uint2 r[4];
#pragma unroll
                for (int k = 0; k < 4; ++k) {
                    int idx = e + k;
                    idx = (idx < e1) ? idx : (e1 - 1);
                    r[k] = packed[idx];
                }
                __builtin_amdgcn_sched_barrier(0);
                float hv[4];
                float4 c[4];
#pragma unroll
                for (int k = 0; k < 4; ++k) {
                    unsigned w0 = r[k].x;
                    hv[k] = bf2f(hb[(size_t)(w0 & 0xffffu) * 64 + lane]);
                    c[k] = wc4[w0 >> 16];
                }
                __builtin_amdgcn_sched_barrier(0);
#pragma unroll
                for (int k = 0; k < 4; ++k) {
                    float nmv = (k < rem) ? __uint_as_float(r[k].y) : 0.f;
                    float a = nmv * hv[k];
                    g0 = fmaf(c[k].x, a, g0);
                    g1 = fmaf(c[k].y, a, g1);
                    g2 = fmaf(c[k].z, a, g2);
                    g3 = fmaf(c[k].w, a, g3);
                }
            }
        }
        gt[jj][lane]       = f2bf(g0);
        gt[jj][64 + lane]  = f2bf(g1);
        gt[jj][128 + lane] = f2bf(g2);
        gt[jj][192 + lane] = f2bf(g3);
    }
    __syncthreads();    // tile rows come from all 4 waves

    // ---------------- Phase 2: MFMA for o-tile wv ----------------
    const float bo0 = bias[wv * 16 + l15];

    f32x4 a0 = {0.f, 0.f, 0.f, 0.f};
#pragma unroll
    for (int ks = 0; ks < 8; ++ks) {
        u32x4 af = *reinterpret_cast<const u32x4*>(&gt[l15][ks * 32 + lg * 8]);
        u32x4 b0 = *reinterpret_cast<const u32x4*>(Wt + (wv * 16 + l15) * 256 + ks * 32 + lg * 8);
        asm volatile("v_mfma_f32_16x16x32_bf16 %0, %1, %2, %0"
                     : "+v"(a0) : "v"(af), "v"(b0));
    }
    asm volatile("s_nop 7\n\ts_nop 7" ::: "memory");

#pragma unroll
    for (int r = 0; r < 4; ++r) {
        const int n = n0 + lg * 4 + r;
        if (n < N) {
            float v0 = a0[r] + bo0;
            out[(size_t)n * 64 + wv * 16 + l15] = v0 > 0.f ? v0 : 0.f;
        }
    }
}

// ============================ Fallback path ============================

__global__ __launch_bounds__(256) void hb_kernel(const float* __restrict__ h,
                                                 const float* __restrict__ weight,
                                                 float* __restrict__ Hb, int N) {
    __shared__ float sh[16][64];
    const int t = threadIdx.x;
    const int b = t >> 6;
    const int o = t & 63;
    float wcol[64];
#pragma unroll
    for (int i = 0; i < 64; ++i) wcol[i] = weight[b * 4096 + i * 64 + o];
    for (int node0 = blockIdx.x * 16; node0 < N; node0 += gridDim.x * 16) {
        __syncthreads();
#pragma unroll
        for (int p = 0; p < 4; ++p) {
            int idx = p * 256 + t;
            int r = idx >> 6, c = idx & 63;
            int node = node0 + r;
            sh[r][c] = (node < N) ? h[(size_t)node * 64 + c] : 0.f;
        }
        __syncthreads();
        int rmax = (N - node0 < 16) ? (N - node0) : 16;
        for (int r = 0; r < rmax; ++r) {
            float acc = 0.f;
#pragma unroll
            for (int i = 0; i < 64; ++i) acc += sh[r][i] * wcol[i];
            Hb[(size_t)(node0 + r) * 256 + t] = acc;
        }
    }
}

__global__ __launch_bounds__(256) void edge_kernel(const float* __restrict__ Hb,
                                                   const float* __restrict__ w_comp,
                                                   const float* __restrict__ edge_norm,
                                                   const int* __restrict__ src,
                                                   const int* __restrict__ dst,
                                                   const int* __restrict__ etype,
                                                   float* __restrict__ out, int E) {
    const int lane = threadIdx.x & 63;
    const int gwave = (blockIdx.x * blockDim.x + threadIdx.x) >> 6;
    const int nwaves = (gridDim.x * blockDim.x) >> 6;
    const int chunk = (E + nwaves - 1) / nwaves;
    const int e0 = gwave * chunk;
    const int e1 = (e0 + chunk < E) ? (e0 + chunk) : E;
    for (int e = e0; e < e1; ++e) {
        int s = src[e];
        int d = dst[e];
        int r = etype[e];
        float nm = edge_norm[e];
        const float* hbp = Hb + (size_t)s * 256;
        const float* cf = w_comp + r * 4;
        float v = cf[0] * hbp[lane] + cf[1] * hbp[64 + lane] + cf[2] * hbp[128 + lane] +
                  cf[3] * hbp[192 + lane];
        atomicAdd(&out[(size_t)d * 64 + lane], v * nm);
    }
}

__global__ __launch_bounds__(256) void bias_relu_kernel(float* __restrict__ out,
                                                        const float* __restrict__ bias,
                                                        int total) {
    int i = blockIdx.x * blockDim.x + threadIdx.x;
    int stride = gridDim.x * blockDim.x;
    for (; i < total; i += stride) {
        float v = out[i] + bias[i & 63];
        out[i] = v > 0.f ? v : 0.f;
    }
}

// ============================ Launch ============================

extern "C" void kernel_launch(void* const* d_in, const int* in_sizes, int n_in,
                              void* d_out, int out_size, void* d_ws, size_t ws_size,
                              hipStream_t stream) {
    const float* h         = (const float*)d_in[0];
    const float* weight    = (const float*)d_in[1];
    const float* w_comp    = (const float*)d_in[2];
    const float* bias      = (const float*)d_in[3];
    const float* edge_norm = (const float*)d_in[4];
    const int*   src       = (const int*)d_in[5];
    const int*   dst       = (const int*)d_in[6];
    const int*   etype     = (const int*)d_in[7];
    float* out = (float*)d_out;

    const int N = in_sizes[0] / 64;
    const int E = in_sizes[4];
    const int nb = (N + 255) / 256;
    const int CH = (((E + NCHUNK - 1) / NCHUNK) + 3) & ~3;   // chunk size, x4 aligned
    const int RS = (N + NRANGE - 1) / NRANGE;                // bins per range

    // workspace: counts | packed | offsets,bsum | Wt | hb
    size_t cntBytes    = (size_t)NCHUNK * N * sizeof(int);
    size_t packedBytes = (size_t)E * 8;
    size_t offBytes    = (size_t)(N + 1) * sizeof(int);
    size_t bsumBytes   = (size_t)nb * sizeof(int);
    size_t wtBytes     = (size_t)64 * 256 * sizeof(unsigned short);
    size_t hbBytes     = (size_t)N * 64 * sizeof(unsigned short);
    size_t need        = cntBytes + packedBytes + offBytes + bsumBytes + wtBytes + hbBytes + 16384;

    if (ws_size >= need && nb <= 256 && RS <= MAXBIN && N <= 65536) {
        char* p = (char*)d_ws;
        int* counts   = (int*)p;
        uint2* packed = (uint2*)(p + cntBytes);
        int* offsets  = (int*)(p + cntBytes + packedBytes);
        int* bsum     = offsets + (N + 1);
        size_t wtOff  = ((cntBytes + packedBytes + offBytes + bsumBytes) + 255) & ~(size_t)255;
        unsigned short* Wt = (unsigned short*)(p + wtOff);
        size_t hbOff  = (wtOff + wtBytes + 255) & ~(size_t)255;
        unsigned short* hb = (unsigned short*)(p + hbOff);

        prep_kernel<<<1024, 256, 0, stream>>>(weight, Wt, h, hb, N * 16);
        hist2_kernel<<<NCHUNK * NRANGE, 256, 0, stream>>>(dst, counts, N, E, CH, RS);
        scan1_kernel<<<nb, 256, 0, stream>>>(counts, bsum, N);
        scan23_kernel<<<nb, 256, 0, stream>>>(counts, bsum, nb, offsets, N, E);
        fill2_kernel<<<NCHUNK * NRANGE, 256, 0, stream>>>(src, dst, etype, edge_norm,
                                                          counts, packed, N, E, CH, RS);
        const int ntiles = (N + 15) >> 4;
        fused_kernel<<<ntiles, 256, 0, stream>>>(packed, offsets, hb, (const float4*)w_comp,
                                                 Wt, bias, out, N);
    } else if (ws_size >= (size_t)N * 256 * sizeof(float)) {
        float* Hb = (float*)d_ws;
        hipMemsetAsync(d_out, 0, (size_t)N * 64 * sizeof(float), stream);
        hb_kernel<<<1024, 256, 0, stream>>>(h, weight, Hb, N);
        edge_kernel<<<2048, 256, 0, stream>>>(Hb, w_comp, edge_norm, src, dst, etype, out, E);
        bias_relu_kernel<<<2048, 256, 0, stream>>>(out, bias, N * 64);
    }
}

// Round 20
// 83.095 us; speedup vs baseline: 1.3410x; 1.0570x over previous
//
#include <hip/hip_runtime.h>

// RGCN layer, basis decomposition — CSR-reordered formulation.
//
//   G[n][b][i] = sum_{e: dst[e]==n} (norm_e * w_comp[etype_e][b]) * h[src_e][i]
//   out[n][o]  = relu( sum_b sum_i G[n][b][i] * weight[b][i][o] + bias[o] )
//
// CSR build: LDS-privatized counting sort, zero global atomics (NCHUNK=64).
// Records 8B {src|etype<<16, norm-f32} (N <= 65536).
// Round-20: hist2/fill2 blockDim 256 -> 1024. Their grid is NCHUNK*NRANGE=256
//   blocks = 1 block/CU; at 4 waves/block the scattered packed[] stores and
//   bins atomics ran at 12.5% occupancy (round-17/19 arithmetic: CSR build
//   ~35-45us of the total). 16 waves/block = 4x latency hiding, same traffic.
// fused: 4 waves/tile (round-19), per-node loop w/ bounded masked tail.

constexpr int NCHUNK = 64;   // edge chunks
constexpr int NRANGE = 4;    // node ranges (LDS bins = ceil(N/NRANGE))
constexpr int MAXBIN = 12800; // 51.2KB LDS; requires N <= NRANGE*MAXBIN

typedef unsigned int u32x4 __attribute__((ext_vector_type(4)));
typedef float f32x4 __attribute__((ext_vector_type(4)));

static __device__ __forceinline__ unsigned short f2bf(float f) {
    unsigned u = __float_as_uint(f);
    u = (u + 0x7fffu + ((u >> 16) & 1u)) >> 16;   // round-to-nearest-even
    return (unsigned short)u;
}
static __device__ __forceinline__ float bf2f(unsigned short v) {
    return __uint_as_float(((unsigned)v) << 16);
}

// ============================ prep: W->bf16 o-major  +  h->bf16 ============================
__global__ __launch_bounds__(256) void prep_kernel(const float* __restrict__ weight,
                                                   unsigned short* __restrict__ Wt,
                                                   const float* __restrict__ h,
                                                   unsigned short* __restrict__ hb,
                                                   int total4) {   // total4 = N*64/4
    int i = blockIdx.x * blockDim.x + threadIdx.x;
    int st = gridDim.x * blockDim.x;
    if (i < 16384) {
        int o = i >> 8, k = i & 255;
        Wt[i] = f2bf(weight[k * 64 + o]);
    }
    for (int q = i; q < total4; q += st) {
        float4 v = ((const float4*)h)[q];
        ushort4 o4;
        o4.x = f2bf(v.x); o4.y = f2bf(v.y); o4.z = f2bf(v.z); o4.w = f2bf(v.w);
        ((ushort4*)hb)[q] = o4;
    }
}

// ============================ hist (no global atomics, 1024 threads) ============================

__global__ __launch_bounds__(1024) void hist2_kernel(const int* __restrict__ dst,
                                                     int* __restrict__ counts,
                                                     int N, int E, int CH, int RS) {
    __shared__ int bins[MAXBIN];
    const int c = blockIdx.x / NRANGE;
    const int r = blockIdx.x % NRANGE;
    const int lo = r * RS;
    const int hi = (lo + RS < N) ? (lo + RS) : N;
    const int nbin = hi - lo;
    for (int i = threadIdx.x; i < nbin; i += 1024) bins[i] = 0;
    __syncthreads();

    const int e0 = c * CH;
    const int e1 = (e0 + CH < E) ? (e0 + CH) : E;
    if (e0 < E) {
        const int cnt = e1 - e0;
        const int nq = cnt >> 2;
        const int4* d4p = (const int4*)(dst + e0);
        for (int q = threadIdx.x; q < nq; q += 1024) {
            int4 d4 = d4p[q];
            if (d4.x >= lo && d4.x < hi) atomicAdd(&bins[d4.x - lo], 1);
            if (d4.y >= lo && d4.y < hi) atomicAdd(&bins[d4.y - lo], 1);
            if (d4.z >= lo && d4.z < hi) atomicAdd(&bins[d4.z - lo], 1);
            if (d4.w >= lo && d4.w < hi) atomicAdd(&bins[d4.w - lo], 1);
        }
        int rem = cnt & 3;
        if ((int)threadIdx.x < rem) {
            int d = dst[e0 + (nq << 2) + threadIdx.x];
            if (d >= lo && d < hi) atomicAdd(&bins[d - lo], 1);
        }
    }
    __syncthreads();
    int* crow = counts + (size_t)c * N + lo;
    for (int i = threadIdx.x; i < nbin; i += 1024) crow[i] = bins[i];
}

// ============================ scan ============================

__global__ __launch_bounds__(256) void scan1_kernel(const int* __restrict__ counts,
                                                    int* __restrict__ bsum, int N) {
    __shared__ int s[256];
    int t = threadIdx.x;
    int n = blockIdx.x * 256 + t;
    int sum = 0;
    if (n < N) {
        for (int c = 0; c < NCHUNK; ++c) sum += counts[(size_t)c * N + n];
    }
    s[t] = sum;
    __syncthreads();
    for (int off = 128; off > 0; off >>= 1) {
        if (t < off) s[t] += s[t + off];
        __syncthreads();
    }
    if (t == 0) bsum[blockIdx.x] = s[0];
}

// merged scan2+scan3
__global__ __launch_bounds__(256) void scan23_kernel(int* __restrict__ counts,
                                                     const int* __restrict__ bsum, int nb,
                                                     int* __restrict__ offsets,
                                                     int N, int E) {
    __shared__ int sb[256];
    __shared__ int s[256];
    int t = threadIdx.x;
    sb[t] = (t < nb) ? bsum[t] : 0;
    __syncthreads();
    for (int off = 1; off < 256; off <<= 1) {
        int x = (t >= off) ? sb[t - off] : 0;
        __syncthreads();
        sb[t] += x;
        __syncthreads();
    }
    int n = blockIdx.x * 256 + t;
    int sum = 0;
    if (n < N) {
        for (int c = 0; c < NCHUNK; ++c) sum += counts[(size_t)c * N + n];
    }
    s[t] = sum;
    __syncthreads();
    for (int off = 1; off < 256; off <<= 1) {
        int x = (t >= off) ? s[t - off] : 0;
        __syncthreads();
        s[t] += x;
        __syncthreads();
    }
    const int blockpre = (blockIdx.x > 0) ? sb[blockIdx.x - 1] : 0;
    if (n < N) {
        int run = s[t] - sum + blockpre;
        offsets[n] = run;
        for (int c = 0; c < NCHUNK; ++c) {
            int v = counts[(size_t)c * N + n];
            counts[(size_t)c * N + n] = run;
            run += v;
        }
    }
    if (blockIdx.x == 0 && t == 0) offsets[N] = E;
}

// ============================ fill (LDS cursors, 8B records, 1024 threads) ============================

__global__ __launch_bounds__(1024) void fill2_kernel(const int* __restrict__ src,
                                                     const int* __restrict__ dst,
                                                     const int* __restrict__ etype,
                                                     const float* __restrict__ norm,
                                                     const int* __restrict__ offs,
                                                     uint2* __restrict__ packed,
                                                     int N, int E, int CH, int RS) {
    __shared__ int cur[MAXBIN];
    const int c = blockIdx.x / NRANGE;
    const int r = blockIdx.x % NRANGE;
    const int lo = r * RS;
    const int hi = (lo + RS < N) ? (lo + RS) : N;
    const int nbin = hi - lo;
    const int* orow = offs + (size_t)c * N + lo;
    for (int i = threadIdx.x; i < nbin; i += 1024) cur[i] = orow[i];
    __syncthreads();

    const int e0 = c * CH;
    const int e1 = (e0 + CH < E) ? (e0 + CH) : E;
    if (e0 >= E) return;
    const int cnt = e1 - e0;
    const int nq = cnt >> 2;
    const int4* d4p = (const int4*)(dst + e0);
    const int4* s4p = (const int4*)(src + e0);
    const int4* t4p = (const int4*)(etype + e0);
    const float4* n4p = (const float4*)(norm + e0);
    for (int q = threadIdx.x; q < nq; q += 1024) {
        int4 d4 = d4p[q];
        int4 s4 = s4p[q];
        int4 t4 = t4p[q];
        float4 n4 = n4p[q];
        if (d4.x >= lo && d4.x < hi) {
            int pos = atomicAdd(&cur[d4.x - lo], 1);
            packed[pos] = make_uint2((unsigned)s4.x | ((unsigned)t4.x << 16),
                                     __float_as_uint(n4.x));
        }
        if (d4.y >= lo && d4.y < hi) {
            int pos = atomicAdd(&cur[d4.y - lo], 1);
            packed[pos] = make_uint2((unsigned)s4.y | ((unsigned)t4.y << 16),
                                     __float_as_uint(n4.y));
        }
        if (d4.z >= lo && d4.z < hi) {
            int pos = atomicAdd(&cur[d4.z - lo], 1);
            packed[pos] = make_uint2((unsigned)s4.z | ((unsigned)t4.z << 16),
                                     __float_as_uint(n4.z));
        }
        if (d4.w >= lo && d4.w < hi) {
            int pos = atomicAdd(&cur[d4.w - lo], 1);
            packed[pos] = make_uint2((unsigned)s4.w | ((unsigned)t4.w << 16),
                                     __float_as_uint(n4.w));
        }
    }
    int rem = cnt & 3;
    if ((int)threadIdx.x < rem) {
        int i = e0 + (nq << 2) + threadIdx.x;
        int d = dst[i];
        if (d >= lo && d < hi) {
            int pos = atomicAdd(&cur[d - lo], 1);
            packed[pos] = make_uint2((unsigned)src[i] | ((unsigned)etype[i] << 16),
                                     __float_as_uint(norm[i]));
        }
    }
}

// ============================ Fused aggregate + MFMA transform (4 waves/tile) ============================
// Block = 4 waves = ONE tile. Wave wv aggregates nodes n0+wv*4..+3 (per-node
// loop: full 8-batches + bounded masked tail), stages bf16 rows in the shared
// LDS tile; __syncthreads; computes o-tile wv via 8 MFMA.
__global__ __launch_bounds__(256) void fused_kernel(const uint2* __restrict__ packed,
                                                    const int* __restrict__ offsets,
                                                    const unsigned short* __restrict__ hb,
                                                    const float4* __restrict__ wc4,
                                                    const unsigned short* __restrict__ Wt,
                                                    const float* __restrict__ bias,
                                                    float* __restrict__ out, int N) {
    __shared__ unsigned short gt[16][272];
    const int t = threadIdx.x;
    const int lane = t & 63;
    const int wv = __builtin_amdgcn_readfirstlane(t >> 6);   // provably uniform
    const int l15 = lane & 15;
    const int lg = lane >> 4;
    const int n0 = __builtin_amdgcn_readfirstlane(blockIdx.x << 4);

    // ---------------- Phase 1: aggregate 4 nodes ----------------
    for (int j = 0; j < 4; ++j) {
        const int jj = wv * 4 + j;
        const int n = n0 + jj;
        float g0 = 0.f, g1 = 0.f, g2 = 0.f, g3 = 0.f;
        if (n < N) {
            const int e0 = offsets[n];
            const int e1 = offsets[n + 1];
            int e = e0;
            for (; e + 8 <= e1; e += 8) {
                uint2 r[8];
#pragma unroll
                for (int k = 0; k < 8; ++k) r[k] = packed[e + k];
                __builtin_amdgcn_sched_barrier(0);
                float hv[8];
                float4 c[8];
#pragma unroll
                for (int k = 0; k < 8; ++k) {
                    unsigned w0 = r[k].x;
                    hv[k] = bf2f(hb[(size_t)(w0 & 0xffffu) * 64 + lane]);
                    c[k] = wc4[w0 >> 16];
                }
                __builtin_amdgcn_sched_barrier(0);
#pragma unroll
                for (int k = 0; k < 8; ++k) {
                    float a = __uint_as_float(r[k].y) * hv[k];
                    g0 = fmaf(c[k].x, a, g0);
                    g1 = fmaf(c[k].y, a, g1);
                    g2 = fmaf(c[k].z, a, g2);
                    g3 = fmaf(c[k].w, a, g3);
                }
            }
            const int rem = e1 - e;
            if (rem > 4) {          // masked 8-batch, waste <= 3
                uint2 r[8];
#pragma unroll
                for (int k = 0; k < 8; ++k) {
                    int idx = e + k;
                    idx = (idx < e1) ? idx : (e1 - 1);
                    r[k] = packed[idx];
                }
                __builtin_amdgcn_sched_barrier(0);
                float hv[8];
                float4 c[8];
#pragma unroll
                for (int k = 0; k < 8; ++k) {
                    unsigned w0 = r[k].x;
                    hv[k] = bf2f(hb[(size_t)(w0 & 0xffffu) * 64 + lane]);
                    c[k] = wc4[w0 >> 16];
                }
                __builtin_amdgcn_sched_barrier(0);
#pragma unroll
                for (int k = 0; k < 8; ++k) {
                    float nmv = (k < rem) ? __uint_as_float(r[k].y) : 0.f;
                    float a = nmv * hv[k];
                    g0 = fmaf(c[k].x, a, g0);
                    g1 = fmaf(c[k].y, a, g1);
                    g2 = fmaf(c[k].z, a, g2);
                    g3 = fmaf(c[k].w, a, g3);
                }
            } else if (rem > 0) {   // masked 4-batch, waste <= 3
                uint2 r[4];
#pragma unroll
                for (int k = 0; k < 4; ++k) {
                    int idx = e + k;
                    idx = (idx < e1) ? idx : (e1 - 1);
                    r[k] = packed[idx];
                }
                __builtin_amdgcn_sched_barrier(0);
                float hv[4];
                float4 c[4];
#pragma unroll
                for (int k = 0; k < 4; ++k) {
                    unsigned w0 = r[k].x;
                    hv[k] = bf2f(hb[(size_t)(w0 & 0xffffu) * 64 + lane]);
                    c[k] = wc4[w0 >> 16];
                }
                __builtin_amdgcn_sched_barrier(0);
#pragma unroll
                for (int k = 0; k < 4; ++k) {
                    float nmv = (k < rem) ? __uint_as_float(r[k].y) : 0.f;
                    float a = nmv * hv[k];
                    g0 = fmaf(c[k].x, a, g0);
                    g1 = fmaf(c[k].y, a, g1);
                    g2 = fmaf(c[k].z, a, g2);
                    g3 = fmaf(c[k].w, a, g3);
                }
            }
        }
        gt[jj][lane]       = f2bf(g0);
        gt[jj][64 + lane]  = f2bf(g1);
        gt[jj][128 + lane] = f2bf(g2);
        gt[jj][192 + lane] = f2bf(g3);
    }
    __syncthreads();    // tile rows come from all 4 waves

    // ---------------- Phase 2: MFMA for o-tile wv ----------------
    const float bo0 = bias[wv * 16 + l15];

    f32x4 a0 = {0.f, 0.f, 0.f, 0.f};
#pragma unroll
    for (int ks = 0; ks < 8; ++ks) {
        u32x4 af = *reinterpret_cast<const u32x4*>(&gt[l15][ks * 32 + lg * 8]);
        u32x4 b0 = *reinterpret_cast<const u32x4*>(Wt + (wv * 16 + l15) * 256 + ks * 32 + lg * 8);
        asm volatile("v_mfma_f32_16x16x32_bf16 %0, %1, %2, %0"
                     : "+v"(a0) : "v"(af), "v"(b0));
    }
    asm volatile("s_nop 7\n\ts_nop 7" ::: "memory");

#pragma unroll
    for (int r = 0; r < 4; ++r) {
        const int n = n0 + lg * 4 + r;
        if (n < N) {
            float v0 = a0[r] + bo0;
            out[(size_t)n * 64 + wv * 16 + l15] = v0 > 0.f ? v0 : 0.f;
        }
    }
}

// ============================ Fallback path ============================

__global__ __launch_bounds__(256) void hb_kernel(const float* __restrict__ h,
                                                 const float* __restrict__ weight,
                                                 float* __restrict__ Hb, int N) {
    __shared__ float sh[16][64];
    const int t = threadIdx.x;
    const int b = t >> 6;
    const int o = t & 63;
    float wcol[64];
#pragma unroll
    for (int i = 0; i < 64; ++i) wcol[i] = weight[b * 4096 + i * 64 + o];
    for (int node0 = blockIdx.x * 16; node0 < N; node0 += gridDim.x * 16) {
        __syncthreads();
#pragma unroll
        for (int p = 0; p < 4; ++p) {
            int idx = p * 256 + t;
            int r = idx >> 6, c = idx & 63;
            int node = node0 + r;
            sh[r][c] = (node < N) ? h[(size_t)node * 64 + c] : 0.f;
        }
        __syncthreads();
        int rmax = (N - node0 < 16) ? (N - node0) : 16;
        for (int r = 0; r < rmax; ++r) {
            float acc = 0.f;
#pragma unroll
            for (int i = 0; i < 64; ++i) acc += sh[r][i] * wcol[i];
            Hb[(size_t)(node0 + r) * 256 + t] = acc;
        }
    }
}

__global__ __launch_bounds__(256) void edge_kernel(const float* __restrict__ Hb,
                                                   const float* __restrict__ w_comp,
                                                   const float* __restrict__ edge_norm,
                                                   const int* __restrict__ src,
                                                   const int* __restrict__ dst,
                                                   const int* __restrict__ etype,
                                                   float* __restrict__ out, int E) {
    const int lane = threadIdx.x & 63;
    const int gwave = (blockIdx.x * blockDim.x + threadIdx.x) >> 6;
    const int nwaves = (gridDim.x * blockDim.x) >> 6;
    const int chunk = (E + nwaves - 1) / nwaves;
    const int e0 = gwave * chunk;
    const int e1 = (e0 + chunk < E) ? (e0 + chunk) : E;
    for (int e = e0; e < e1; ++e) {
        int s = src[e];
        int d = dst[e];
        int r = etype[e];
        float nm = edge_norm[e];
        const float* hbp = Hb + (size_t)s * 256;
        const float* cf = w_comp + r * 4;
        float v = cf[0] * hbp[lane] + cf[1] * hbp[64 + lane] + cf[2] * hbp[128 + lane] +
                  cf[3] * hbp[192 + lane];
        atomicAdd(&out[(size_t)d * 64 + lane], v * nm);
    }
}

__global__ __launch_bounds__(256) void bias_relu_kernel(float* __restrict__ out,
                                                        const float* __restrict__ bias,
                                                        int total) {
    int i = blockIdx.x * blockDim.x + threadIdx.x;
    int stride = gridDim.x * blockDim.x;
    for (; i < total; i += stride) {
        float v = out[i] + bias[i & 63];
        out[i] = v > 0.f ? v : 0.f;
    }
}

// ============================ Launch ============================

extern "C" void kernel_launch(void* const* d_in, const int* in_sizes, int n_in,
                              void* d_out, int out_size, void* d_ws, size_t ws_size,
                              hipStream_t stream) {
    const float* h         = (const float*)d_in[0];
    const float* weight    = (const float*)d_in[1];
    const float* w_comp    = (const float*)d_in[2];
    const float* bias      = (const float*)d_in[3];
    const float* edge_norm = (const float*)d_in[4];
    const int*   src       = (const int*)d_in[5];
    const int*   dst       = (const int*)d_in[6];
    const int*   etype     = (const int*)d_in[7];
    float* out = (float*)d_out;

    const int N = in_sizes[0] / 64;
    const int E = in_sizes[4];
    const int nb = (N + 255) / 256;
    const int CH = (((E + NCHUNK - 1) / NCHUNK) + 3) & ~3;   // chunk size, x4 aligned
    const int RS = (N + NRANGE - 1) / NRANGE;                // bins per range

    // workspace: counts | packed | offsets,bsum | Wt | hb
    size_t cntBytes    = (size_t)NCHUNK * N * sizeof(int);
    size_t packedBytes = (size_t)E * 8;
    size_t offBytes    = (size_t)(N + 1) * sizeof(int);
    size_t bsumBytes   = (size_t)nb * sizeof(int);
    size_t wtBytes     = (size_t)64 * 256 * sizeof(unsigned short);
    size_t hbBytes     = (size_t)N * 64 * sizeof(unsigned short);
    size_t need        = cntBytes + packedBytes + offBytes + bsumBytes + wtBytes + hbBytes + 16384;

    if (ws_size >= need && nb <= 256 && RS <= MAXBIN && N <= 65536) {
        char* p = (char*)d_ws;
        int* counts   = (int*)p;
        uint2* packed = (uint2*)(p + cntBytes);
        int* offsets  = (int*)(p + cntBytes + packedBytes);
        int* bsum     = offsets + (N + 1);
        size_t wtOff  = ((cntBytes + packedBytes + offBytes + bsumBytes) + 255) & ~(size_t)255;
        unsigned short* Wt = (unsigned short*)(p + wtOff);
        size_t hbOff  = (wtOff + wtBytes + 255) & ~(size_t)255;
        unsigned short* hb = (unsigned short*)(p + hbOff);

        prep_kernel<<<1024, 256, 0, stream>>>(weight, Wt, h, hb, N * 16);
        hist2_kernel<<<NCHUNK * NRANGE, 1024, 0, stream>>>(dst, counts, N, E, CH, RS);
        scan1_kernel<<<nb, 256, 0, stream>>>(counts, bsum, N);
        scan23_kernel<<<nb, 256, 0, stream>>>(counts, bsum, nb, offsets, N, E);
        fill2_kernel<<<NCHUNK * NRANGE, 1024, 0, stream>>>(src, dst, etype, edge_norm,
                                                           counts, packed, N, E, CH, RS);
        const int ntiles = (N + 15) >> 4;
        fused_kernel<<<ntiles, 256, 0, stream>>>(packed, offsets, hb, (const float4*)w_comp,
                                                 Wt, bias, out, N);
    } else if (ws_size >= (size_t)N * 256 * sizeof(float)) {
        float* Hb = (float*)d_ws;
        hipMemsetAsync(d_out, 0, (size_t)N * 64 * sizeof(float), stream);
        hb_kernel<<<1024, 256, 0, stream>>>(h, weight, Hb, N);
        edge_kernel<<<2048, 256, 0, stream>>>(Hb, w_comp, edge_norm, src, dst, etype, out, E);
        bias_relu_kernel<<<2048, 256, 0, stream>>>(out, bias, N * 64);
    }
}

// Round 21
// 75.179 us; speedup vs baseline: 1.4822x; 1.1053x over previous
//
#include <hip/hip_runtime.h>

// RGCN layer, basis decomposition — CSR-reordered formulation.
//
//   G[n][b][i] = sum_{e: dst[e]==n} (norm_e * w_comp[etype_e][b]) * h[src_e][i]
//   out[n][o]  = relu( sum_b sum_i G[n][b][i] * weight[b][i][o] + bias[o] )
//
// CSR build: LDS-privatized counting sort, zero global atomics (NCHUNK=64).
// Records 8B {src|etype<<16, norm-f32} (N <= 65536).
// Round-21: (a) counts stored as USHORT (per-chunk count <= CH < 2^16):
//   halves hist write + both scan reads (-19MB). Start offsets (32-bit) go to
//   a separate starts[] array. (b) prep (W/h -> bf16) merged into hist2 —
//   hist2 is atomic-bound at 4% VALU, the streaming conversion rides free.
//   5 launches total.
// fused: 4 waves/tile (round-19), per-node loop w/ bounded masked tail.

constexpr int NCHUNK = 64;   // edge chunks
constexpr int NRANGE = 4;    // node ranges (LDS bins = ceil(N/NRANGE))
constexpr int MAXBIN = 12800; // 51.2KB LDS; requires N <= NRANGE*MAXBIN

typedef unsigned int u32x4 __attribute__((ext_vector_type(4)));
typedef float f32x4 __attribute__((ext_vector_type(4)));

static __device__ __forceinline__ unsigned short f2bf(float f) {
    unsigned u = __float_as_uint(f);
    u = (u + 0x7fffu + ((u >> 16) & 1u)) >> 16;   // round-to-nearest-even
    return (unsigned short)u;
}
static __device__ __forceinline__ float bf2f(unsigned short v) {
    return __uint_as_float(((unsigned)v) << 16);
}

// ============================ hist + prep (1024 threads) ============================
// Histogram into LDS bins -> ushort counts row. Also converts W (o-major) and
// h to bf16 (grid-stride; independent of the LDS work, fills idle issue slots).
__global__ __launch_bounds__(1024) void hist2p_kernel(const int* __restrict__ dst,
                                                      unsigned short* __restrict__ countsU,
                                                      int N, int E, int CH, int RS,
                                                      const float* __restrict__ weight,
                                                      unsigned short* __restrict__ Wt,
                                                      const float* __restrict__ h,
                                                      unsigned short* __restrict__ hb,
                                                      int total4) {
    __shared__ int bins[MAXBIN];
    const int c = blockIdx.x / NRANGE;
    const int r = blockIdx.x % NRANGE;
    const int lo = r * RS;
    const int hi = (lo + RS < N) ? (lo + RS) : N;
    const int nbin = hi - lo;
    for (int i = threadIdx.x; i < nbin; i += 1024) bins[i] = 0;

    // ---- prep work (no LDS deps): W -> bf16 o-major, h -> bf16 ----
    {
        int gid = blockIdx.x * 1024 + threadIdx.x;
        int gsz = gridDim.x * 1024;
        if (gid < 16384) {
            int o = gid >> 8, k = gid & 255;
            Wt[gid] = f2bf(weight[k * 64 + o]);
        }
        for (int q = gid; q < total4; q += gsz) {
            float4 v = ((const float4*)h)[q];
            ushort4 o4;
            o4.x = f2bf(v.x); o4.y = f2bf(v.y); o4.z = f2bf(v.z); o4.w = f2bf(v.w);
            ((ushort4*)hb)[q] = o4;
        }
    }
    __syncthreads();

    const int e0 = c * CH;
    const int e1 = (e0 + CH < E) ? (e0 + CH) : E;
    if (e0 < E) {
        const int cnt = e1 - e0;
        const int nq = cnt >> 2;
        const int4* d4p = (const int4*)(dst + e0);
        for (int q = threadIdx.x; q < nq; q += 1024) {
            int4 d4 = d4p[q];
            if (d4.x >= lo && d4.x < hi) atomicAdd(&bins[d4.x - lo], 1);
            if (d4.y >= lo && d4.y < hi) atomicAdd(&bins[d4.y - lo], 1);
            if (d4.z >= lo && d4.z < hi) atomicAdd(&bins[d4.z - lo], 1);
            if (d4.w >= lo && d4.w < hi) atomicAdd(&bins[d4.w - lo], 1);
        }
        int rem = cnt & 3;
        if ((int)threadIdx.x < rem) {
            int d = dst[e0 + (nq << 2) + threadIdx.x];
            if (d >= lo && d < hi) atomicAdd(&bins[d - lo], 1);
        }
    }
    __syncthreads();
    unsigned short* crow = countsU + (size_t)c * N + lo;
    for (int i = threadIdx.x; i < nbin; i += 1024)
        crow[i] = (unsigned short)bins[i];
}

// ============================ scan ============================

__global__ __launch_bounds__(256) void scan1_kernel(const unsigned short* __restrict__ countsU,
                                                    int* __restrict__ bsum, int N) {
    __shared__ int s[256];
    int t = threadIdx.x;
    int n = blockIdx.x * 256 + t;
    int sum = 0;
    if (n < N) {
        for (int c = 0; c < NCHUNK; ++c) sum += (int)countsU[(size_t)c * N + n];
    }
    s[t] = sum;
    __syncthreads();
    for (int off = 128; off > 0; off >>= 1) {
        if (t < off) s[t] += s[t + off];
        __syncthreads();
    }
    if (t == 0) bsum[blockIdx.x] = s[0];
}

// merged scan2+scan3: bsum scanned in LDS; per-(chunk,node) start offsets
// written to starts[] (int); per-node base to offsets[].
__global__ __launch_bounds__(256) void scan23_kernel(const unsigned short* __restrict__ countsU,
                                                     int* __restrict__ starts,
                                                     const int* __restrict__ bsum, int nb,
                                                     int* __restrict__ offsets,
                                                     int N, int E) {
    __shared__ int sb[256];
    __shared__ int s[256];
    int t = threadIdx.x;
    sb[t] = (t < nb) ? bsum[t] : 0;
    __syncthreads();
    for (int off = 1; off < 256; off <<= 1) {
        int x = (t >= off) ? sb[t - off] : 0;
        __syncthreads();
        sb[t] += x;
        __syncthreads();
    }
    int n = blockIdx.x * 256 + t;
    int sum = 0;
    if (n < N) {
        for (int c = 0; c < NCHUNK; ++c) sum += (int)countsU[(size_t)c * N + n];
    }
    s[t] = sum;
    __syncthreads();
    for (int off = 1; off < 256; off <<= 1) {
        int x = (t >= off) ? s[t - off] : 0;
        __syncthreads();
        s[t] += x;
        __syncthreads();
    }
    const int blockpre = (blockIdx.x > 0) ? sb[blockIdx.x - 1] : 0;
    if (n < N) {
        int run = s[t] - sum + blockpre;
        offsets[n] = run;
        for (int c = 0; c < NCHUNK; ++c) {
            int v = (int)countsU[(size_t)c * N + n];
            starts[(size_t)c * N + n] = run;
            run += v;
        }
    }
    if (blockIdx.x == 0 && t == 0) offsets[N] = E;
}

// ============================ fill (LDS cursors, 8B records, 1024 threads) ============================

__global__ __launch_bounds__(1024) void fill2_kernel(const int* __restrict__ src,
                                                     const int* __restrict__ dst,
                                                     const int* __restrict__ etype,
                                                     const float* __restrict__ norm,
                                                     const int* __restrict__ starts,
                                                     uint2* __restrict__ packed,
                                                     int N, int E, int CH, int RS) {
    __shared__ int cur[MAXBIN];
    const int c = blockIdx.x / NRANGE;
    const int r = blockIdx.x % NRANGE;
    const int lo = r * RS;
    const int hi = (lo + RS < N) ? (lo + RS) : N;
    const int nbin = hi - lo;
    const int* orow = starts + (size_t)c * N + lo;
    for (int i = threadIdx.x; i < nbin; i += 1024) cur[i] = orow[i];
    __syncthreads();

    const int e0 = c * CH;
    const int e1 = (e0 + CH < E) ? (e0 + CH) : E;
    if (e0 >= E) return;
    const int cnt = e1 - e0;
    const int nq = cnt >> 2;
    const int4* d4p = (const int4*)(dst + e0);
    const int4* s4p = (const int4*)(src + e0);
    const int4* t4p = (const int4*)(etype + e0);
    const float4* n4p = (const float4*)(norm + e0);
    for (int q = threadIdx.x; q < nq; q += 1024) {
        int4 d4 = d4p[q];
        int4 s4 = s4p[q];
        int4 t4 = t4p[q];
        float4 n4 = n4p[q];
        if (d4.x >= lo && d4.x < hi) {
            int pos = atomicAdd(&cur[d4.x - lo], 1);
            packed[pos] = make_uint2((unsigned)s4.x | ((unsigned)t4.x << 16),
                                     __float_as_uint(n4.x));
        }
        if (d4.y >= lo && d4.y < hi) {
            int pos = atomicAdd(&cur[d4.y - lo], 1);
            packed[pos] = make_uint2((unsigned)s4.y | ((unsigned)t4.y << 16),
                                     __float_as_uint(n4.y));
        }
        if (d4.z >= lo && d4.z < hi) {
            int pos = atomicAdd(&cur[d4.z - lo], 1);
            packed[pos] = make_uint2((unsigned)s4.z | ((unsigned)t4.z << 16),
                                     __float_as_uint(n4.z));
        }
        if (d4.w >= lo && d4.w < hi) {
            int pos = atomicAdd(&cur[d4.w - lo], 1);
            packed[pos] = make_uint2((unsigned)s4.w | ((unsigned)t4.w << 16),
                                     __float_as_uint(n4.w));
        }
    }
    int rem = cnt & 3;
    if ((int)threadIdx.x < rem) {
        int i = e0 + (nq << 2) + threadIdx.x;
        int d = dst[i];
        if (d >= lo && d < hi) {
            int pos = atomicAdd(&cur[d - lo], 1);
            packed[pos] = make_uint2((unsigned)src[i] | ((unsigned)etype[i] << 16),
                                     __float_as_uint(norm[i]));
        }
    }
}

// ============================ Fused aggregate + MFMA transform (4 waves/tile) ============================
// Block = 4 waves = ONE tile. Wave wv aggregates nodes n0+wv*4..+3 (per-node
// loop: full 8-batches + bounded masked tail), stages bf16 rows in the shared
// LDS tile; __syncthreads; computes o-tile wv via 8 MFMA.
__global__ __launch_bounds__(256) void fused_kernel(const uint2* __restrict__ packed,
                                                    const int* __restrict__ offsets,
                                                    const unsigned short* __restrict__ hb,
                                                    const float4* __restrict__ wc4,
                                                    const unsigned short* __restrict__ Wt,
                                                    const float* __restrict__ bias,
                                                    float* __restrict__ out, int N) {
    __shared__ unsigned short gt[16][272];
    const int t = threadIdx.x;
    const int lane = t & 63;
    const int wv = __builtin_amdgcn_readfirstlane(t >> 6);   // provably uniform
    const int l15 = lane & 15;
    const int lg = lane >> 4;
    const int n0 = __builtin_amdgcn_readfirstlane(blockIdx.x << 4);

    // ---------------- Phase 1: aggregate 4 nodes ----------------
    for (int j = 0; j < 4; ++j) {
        const int jj = wv * 4 + j;
        const int n = n0 + jj;
        float g0 = 0.f, g1 = 0.f, g2 = 0.f, g3 = 0.f;
        if (n < N) {
            const int e0 = offsets[n];
            const int e1 = offsets[n + 1];
            int e = e0;
            for (; e + 8 <= e1; e += 8) {
                uint2 r[8];
#pragma unroll
                for (int k = 0; k < 8; ++k) r[k] = packed[e + k];
                __builtin_amdgcn_sched_barrier(0);
                float hv[8];
                float4 c[8];
#pragma unroll
                for (int k = 0; k < 8; ++k) {
                    unsigned w0 = r[k].x;
                    hv[k] = bf2f(hb[(size_t)(w0 & 0xffffu) * 64 + lane]);
                    c[k] = wc4[w0 >> 16];
                }
                __builtin_amdgcn_sched_barrier(0);
#pragma unroll
                for (int k = 0; k < 8; ++k) {
                    float a = __uint_as_float(r[k].y) * hv[k];
                    g0 = fmaf(c[k].x, a, g0);
                    g1 = fmaf(c[k].y, a, g1);
                    g2 = fmaf(c[k].z, a, g2);
                    g3 = fmaf(c[k].w, a, g3);
                }
            }
            const int rem = e1 - e;
            if (rem > 4) {          // masked 8-batch, waste <= 3
                uint2 r[8];
#pragma unroll
                for (int k = 0; k < 8; ++k) {
                    int idx = e + k;
                    idx = (idx < e1) ? idx : (e1 - 1);
                    r[k] = packed[idx];
                }
                __builtin_amdgcn_sched_barrier(0);
                float hv[8];
                float4 c[8];
#pragma unroll
                for (int k = 0; k < 8; ++k) {
                    unsigned w0 = r[k].x;
                    hv[k] = bf2f(hb[(size_t)(w0 & 0xffffu) * 64 + lane]);
                    c[k] = wc4[w0 >> 16];
                }
                __builtin_amdgcn_sched_barrier(0);
#pragma unroll
                for (int k = 0; k < 8; ++k) {
                    float nmv = (k < rem) ? __uint_as_float(r[k].y) : 0.f;
                    float a = nmv * hv[k];
                    g0 = fmaf(c[k].x, a, g0);
                    g1 = fmaf(c[k].y, a, g1);
                    g2 = fmaf(c[k].z, a, g2);
                    g3 = fmaf(c[k].w, a, g3);
                }
            } else if (rem > 0) {   // masked 4-batch, waste <= 3
                uint2 r[4];
#pragma unroll
                for (int k = 0; k < 4; ++k) {
                    int idx = e + k;
                    idx = (idx < e1) ? idx : (e1 - 1);
                    r[k] = packed[idx];
                }
                __builtin_amdgcn_sched_barrier(0);
                float hv[4];
                float4 c[4];
#pragma unroll
                for (int k = 0; k < 4; ++k) {
                    unsigned w0 = r[k].x;
                    hv[k] = bf2f(hb[(size_t)(w0 & 0xffffu) * 64 + lane]);
                    c[k] = wc4[w0 >> 16];
                }
                __builtin_amdgcn_sched_barrier(0);
#pragma unroll
                for (int k = 0; k < 4; ++k) {
                    float nmv = (k < rem) ? __uint_as_float(r[k].y) : 0.f;
                    float a = nmv * hv[k];
                    g0 = fmaf(c[k].x, a, g0);
                    g1 = fmaf(c[k].y, a, g1);
                    g2 = fmaf(c[k].z, a, g2);
                    g3 = fmaf(c[k].w, a, g3);
                }
            }
        }
        gt[jj][lane]       = f2bf(g0);
        gt[jj][64 + lane]  = f2bf(g1);
        gt[jj][128 + lane] = f2bf(g2);
        gt[jj][192 + lane] = f2bf(g3);
    }
    __syncthreads();    // tile rows come from all 4 waves

    // ---------------- Phase 2: MFMA for o-tile wv ----------------
    const float bo0 = bias[wv * 16 + l15];

    f32x4 a0 = {0.f, 0.f, 0.f, 0.f};
#pragma unroll
    for (int ks = 0; ks < 8; ++ks) {
        u32x4 af = *reinterpret_cast<const u32x4*>(&gt[l15][ks * 32 + lg * 8]);
        u32x4 b0 = *reinterpret_cast<const u32x4*>(Wt + (wv * 16 + l15) * 256 + ks * 32 + lg * 8);
        asm volatile("v_mfma_f32_16x16x32_bf16 %0, %1, %2, %0"
                     : "+v"(a0) : "v"(af), "v"(b0));
    }
    asm volatile("s_nop 7\n\ts_nop 7" ::: "memory");

#pragma unroll
    for (int r = 0; r < 4; ++r) {
        const int n = n0 + lg * 4 + r;
        if (n < N) {
            float v0 = a0[r] + bo0;
            out[(size_t)n * 64 + wv * 16 + l15] = v0 > 0.f ? v0 : 0.f;
        }
    }
}

// ============================ Fallback path ============================

__global__ __launch_bounds__(256) void hb_kernel(const float* __restrict__ h,
                                                 const float* __restrict__ weight,
                                                 float* __restrict__ Hb, int N) {
    __shared__ float sh[16][64];
    const int t = threadIdx.x;
    const int b = t >> 6;
    const int o = t & 63;
    float wcol[64];
#pragma unroll
    for (int i = 0; i < 64; ++i) wcol[i] = weight[b * 4096 + i * 64 + o];
    for (int node0 = blockIdx.x * 16; node0 < N; node0 += gridDim.x * 16) {
        __syncthreads();
#pragma unroll
        for (int p = 0; p < 4; ++p) {
            int idx = p * 256 + t;
            int r = idx >> 6, c = idx & 63;
            int node = node0 + r;
            sh[r][c] = (node < N) ? h[(size_t)node * 64 + c] : 0.f;
        }
        __syncthreads();
        int rmax = (N - node0 < 16) ? (N - node0) : 16;
        for (int r = 0; r < rmax; ++r) {
            float acc = 0.f;
#pragma unroll
            for (int i = 0; i < 64; ++i) acc += sh[r][i] * wcol[i];
            Hb[(size_t)(node0 + r) * 256 + t] = acc;
        }
    }
}

__global__ __launch_bounds__(256) void edge_kernel(const float* __restrict__ Hb,
                                                   const float* __restrict__ w_comp,
                                                   const float* __restrict__ edge_norm,
                                                   const int* __restrict__ src,
                                                   const int* __restrict__ dst,
                                                   const int* __restrict__ etype,
                                                   float* __restrict__ out, int E) {
    const int lane = threadIdx.x & 63;
    const int gwave = (blockIdx.x * blockDim.x + threadIdx.x) >> 6;
    const int nwaves = (gridDim.x * blockDim.x) >> 6;
    const int chunk = (E + nwaves - 1) / nwaves;
    const int e0 = gwave * chunk;
    const int e1 = (e0 + chunk < E) ? (e0 + chunk) : E;
    for (int e = e0; e < e1; ++e) {
        int s = src[e];
        int d = dst[e];
        int r = etype[e];
        float nm = edge_norm[e];
        const float* hbp = Hb + (size_t)s * 256;
        const float* cf = w_comp + r * 4;
        float v = cf[0] * hbp[lane] + cf[1] * hbp[64 + lane] + cf[2] * hbp[128 + lane] +
                  cf[3] * hbp[192 + lane];
        atomicAdd(&out[(size_t)d * 64 + lane], v * nm);
    }
}

__global__ __launch_bounds__(256) void bias_relu_kernel(float* __restrict__ out,
                                                        const float* __restrict__ bias,
                                                        int total) {
    int i = blockIdx.x * blockDim.x + threadIdx.x;
    int stride = gridDim.x * blockDim.x;
    for (; i < total; i += stride) {
        float v = out[i] + bias[i & 63];
        out[i] = v > 0.f ? v : 0.f;
    }
}

// ============================ Launch ============================

extern "C" void kernel_launch(void* const* d_in, const int* in_sizes, int n_in,
                              void* d_out, int out_size, void* d_ws, size_t ws_size,
                              hipStream_t stream) {
    const float* h         = (const float*)d_in[0];
    const float* weight    = (const float*)d_in[1];
    const float* w_comp    = (const float*)d_in[2];
    const float* bias      = (const float*)d_in[3];
    const float* edge_norm = (const float*)d_in[4];
    const int*   src       = (const int*)d_in[5];
    const int*   dst       = (const int*)d_in[6];
    const int*   etype     = (const int*)d_in[7];
    float* out = (float*)d_out;

    const int N = in_sizes[0] / 64;
    const int E = in_sizes[4];
    const int nb = (N + 255) / 256;
    const int CH = (((E + NCHUNK - 1) / NCHUNK) + 3) & ~3;   // chunk size, x4 aligned
    const int RS = (N + NRANGE - 1) / NRANGE;                // bins per range

    // workspace: countsU(u16) | starts(i32) | packed | offsets,bsum | Wt | hb
    size_t cntBytes    = (size_t)NCHUNK * N * sizeof(unsigned short);
    size_t startBytes  = (size_t)NCHUNK * N * sizeof(int);
    size_t packedBytes = (size_t)E * 8;
    size_t offBytes    = (size_t)(N + 1) * sizeof(int);
    size_t bsumBytes   = (size_t)nb * sizeof(int);
    size_t wtBytes     = (size_t)64 * 256 * sizeof(unsigned short);
    size_t hbBytes     = (size_t)N * 64 * sizeof(unsigned short);
    size_t need = cntBytes + startBytes + packedBytes + offBytes + bsumBytes +
                  wtBytes + hbBytes + 16384;

    if (ws_size >= need && nb <= 256 && RS <= MAXBIN && N <= 65536 && CH <= 65535) {
        char* p = (char*)d_ws;
        unsigned short* countsU = (unsigned short*)p;
        int* starts   = (int*)(p + cntBytes);
        uint2* packed = (uint2*)(p + cntBytes + startBytes);
        int* offsets  = (int*)(p + cntBytes + startBytes + packedBytes);
        int* bsum     = offsets + (N + 1);
        size_t wtOff  = ((cntBytes + startBytes + packedBytes + offBytes + bsumBytes) + 255)
                        & ~(size_t)255;
        unsigned short* Wt = (unsigned short*)(p + wtOff);
        size_t hbOff  = (wtOff + wtBytes + 255) & ~(size_t)255;
        unsigned short* hb = (unsigned short*)(p + hbOff);

        hist2p_kernel<<<NCHUNK * NRANGE, 1024, 0, stream>>>(dst, countsU, N, E, CH, RS,
                                                            weight, Wt, h, hb, N * 16);
        scan1_kernel<<<nb, 256, 0, stream>>>(countsU, bsum, N);
        scan23_kernel<<<nb, 256, 0, stream>>>(countsU, starts, bsum, nb, offsets, N, E);
        fill2_kernel<<<NCHUNK * NRANGE, 1024, 0, stream>>>(src, dst, etype, edge_norm,
                                                           starts, packed, N, E, CH, RS);
        const int ntiles = (N + 15) >> 4;
        fused_kernel<<<ntiles, 256, 0, stream>>>(packed, offsets, hb, (const float4*)w_comp,
                                                 Wt, bias, out, N);
    } else if (ws_size >= (size_t)N * 256 * sizeof(float)) {
        float* Hb = (float*)d_ws;
        hipMemsetAsync(d_out, 0, (size_t)N * 64 * sizeof(float), stream);
        hb_kernel<<<1024, 256, 0, stream>>>(h, weight, Hb, N);
        edge_kernel<<<2048, 256, 0, stream>>>(Hb, w_comp, edge_norm, src, dst, etype, out, E);
        bias_relu_kernel<<<2048, 256, 0, stream>>>(out, bias, N * 64);
    }
}